// Round 4
// baseline (801.237 us; speedup 1.0000x reference)
//
#include <hip/hip_runtime.h>
#include <cstdint>
#include <cstddef>

#define N_NODES 100000
#define N_EDGES 500000
#define N_RELS  200
#define N_BASE  50
#define INIT_D  100
#define FEAT_D  128
#define N_CLS   50
#define BN_EPS  1e-5f

#define SCAN_BLK 1024                      // elements per scan block
#define NB_SCAN  ((N_NODES + SCAN_BLK - 1) / SCAN_BLK)   // 98

// ---------- REL[r][f] = (rel_wt[r] @ emb_e) @ W_e_init ----------
__global__ __launch_bounds__(128)
void rel_kernel(const float* __restrict__ rel_wt, const float* __restrict__ emb_e,
                const float* __restrict__ W_e, float* __restrict__ REL) {
  int r = blockIdx.x;
  int t = threadIdx.x;
  __shared__ float T[INIT_D];
  if (t < INIT_D) {
    float a = 0.f;
    for (int b = 0; b < N_BASE; ++b)
      a += rel_wt[r * N_BASE + b] * emb_e[b * INIT_D + t];
    T[t] = a;
  }
  __syncthreads();
  float a = 0.f;
  for (int k = 0; k < INIT_D; ++k)
    a += T[k] * W_e[k * FEAT_D + t];
  REL[r * FEAT_D + t] = a;
}

// ---------- Wcomb = W_h_init @ aggre_W  (100 x 128) ----------
__global__ __launch_bounds__(128)
void wcomb_kernel(const float* __restrict__ W_h, const float* __restrict__ aggre_W,
                  float* __restrict__ WC) {
  int i = blockIdx.x;
  int j = threadIdx.x;
  __shared__ float row[FEAT_D];
  row[j] = W_h[i * FEAT_D + j];
  __syncthreads();
  float a = 0.f;
  for (int f = 0; f < FEAT_D; ++f)
    a += row[f] * aggre_W[f * FEAT_D + j];
  WC[i * FEAT_D + j] = a;
}

// ---------- H0[n] = relu(emb_h[n] @ WC + b) ; one node per thread ----------
__global__ __launch_bounds__(256)
void h0_kernel(const float* __restrict__ emb_h, const float* __restrict__ WC,
               const float* __restrict__ bias, float* __restrict__ H, int nNodes) {
  __shared__ float WT[FEAT_D * INIT_D];  // WT[j*100+k] = WC[k*128+j]
  __shared__ float bs[FEAT_D];
  int t = threadIdx.x;
  for (int i = t; i < FEAT_D * INIT_D; i += 256) {
    int k = i >> 7, j = i & 127;
    WT[j * INIT_D + k] = WC[i];
  }
  if (t < FEAT_D) bs[t] = bias[t];
  __syncthreads();
  for (int n = blockIdx.x * 256 + t; n < nNodes; n += gridDim.x * 256) {
    float x[INIT_D];
    const float4* xp = (const float4*)(emb_h + (size_t)n * INIT_D);
#pragma unroll
    for (int q = 0; q < 25; ++q) {
      float4 v = xp[q];
      x[4 * q + 0] = v.x; x[4 * q + 1] = v.y; x[4 * q + 2] = v.z; x[4 * q + 3] = v.w;
    }
    float* orow = H + (size_t)n * FEAT_D;
    for (int j4 = 0; j4 < 32; ++j4) {
      float4 a;
      a.x = bs[4 * j4 + 0]; a.y = bs[4 * j4 + 1];
      a.z = bs[4 * j4 + 2]; a.w = bs[4 * j4 + 3];
      const float4* w0 = (const float4*)&WT[(4 * j4 + 0) * INIT_D];
      const float4* w1 = (const float4*)&WT[(4 * j4 + 1) * INIT_D];
      const float4* w2 = (const float4*)&WT[(4 * j4 + 2) * INIT_D];
      const float4* w3 = (const float4*)&WT[(4 * j4 + 3) * INIT_D];
#pragma unroll
      for (int q = 0; q < 25; ++q) {
        float4 v0 = w0[q], v1 = w1[q], v2 = w2[q], v3 = w3[q];
        a.x = fmaf(x[4*q+0], v0.x, a.x); a.x = fmaf(x[4*q+1], v0.y, a.x);
        a.x = fmaf(x[4*q+2], v0.z, a.x); a.x = fmaf(x[4*q+3], v0.w, a.x);
        a.y = fmaf(x[4*q+0], v1.x, a.y); a.y = fmaf(x[4*q+1], v1.y, a.y);
        a.y = fmaf(x[4*q+2], v1.z, a.y); a.y = fmaf(x[4*q+3], v1.w, a.y);
        a.z = fmaf(x[4*q+0], v2.x, a.z); a.z = fmaf(x[4*q+1], v2.y, a.z);
        a.z = fmaf(x[4*q+2], v2.z, a.z); a.z = fmaf(x[4*q+3], v2.w, a.z);
        a.w = fmaf(x[4*q+0], v3.x, a.w); a.w = fmaf(x[4*q+1], v3.y, a.w);
        a.w = fmaf(x[4*q+2], v3.z, a.w); a.w = fmaf(x[4*q+3], v3.w, a.w);
      }
      a.x = fmaxf(a.x, 0.f); a.y = fmaxf(a.y, 0.f);
      a.z = fmaxf(a.z, 0.f); a.w = fmaxf(a.w, 0.f);
      *(float4*)(orow + 4 * j4) = a;
    }
  }
}

// ---------- CSR build: histogram of dst ----------
__global__ __launch_bounds__(256)
void hist_kernel(const int* __restrict__ dst, int* __restrict__ deg, int nEdges) {
  for (int e = blockIdx.x * 256 + threadIdx.x; e < nEdges; e += gridDim.x * 256)
    atomicAdd(&deg[dst[e]], 1);
}

// ---------- CSR build: per-block sums of deg ----------
__global__ __launch_bounds__(256)
void scanA_kernel(const int* __restrict__ deg, int* __restrict__ bsum, int n) {
  __shared__ int red[256];
  int t = threadIdx.x;
  int base = blockIdx.x * SCAN_BLK + t * 4;
  int s = 0;
#pragma unroll
  for (int q = 0; q < 4; ++q) {
    int i = base + q;
    s += (i < n) ? deg[i] : 0;
  }
  red[t] = s;
  __syncthreads();
  for (int off = 128; off > 0; off >>= 1) {
    if (t < off) red[t] += red[t + off];
    __syncthreads();
  }
  if (t == 0) bsum[blockIdx.x] = red[0];
}

// ---------- CSR build: sequential scan of block sums (tiny) ----------
__global__ void scanB_kernel(int* __restrict__ bsum, int nb, int* __restrict__ off) {
  int run = 0;
  for (int i = 0; i < nb; ++i) {
    int v = bsum[i];
    bsum[i] = run;
    run += v;
  }
  off[N_NODES] = run;
}

// ---------- CSR build: final offsets (exclusive scan) + cursor copy ----------
__global__ __launch_bounds__(256)
void scanC_kernel(const int* __restrict__ deg, const int* __restrict__ bsum,
                  int* __restrict__ off, int* __restrict__ cur, int n) {
  __shared__ int lds[256];
  int t = threadIdx.x;
  int base = blockIdx.x * SCAN_BLK + t * 4;
  int d[4];
  int s = 0;
#pragma unroll
  for (int q = 0; q < 4; ++q) {
    int i = base + q;
    d[q] = (i < n) ? deg[i] : 0;
    s += d[q];
  }
  lds[t] = s;
  __syncthreads();
  for (int o = 1; o < 256; o <<= 1) {
    int v = (t >= o) ? lds[t - o] : 0;
    __syncthreads();
    lds[t] += v;
    __syncthreads();
  }
  int excl = lds[t] - s + bsum[blockIdx.x];
#pragma unroll
  for (int q = 0; q < 4; ++q) {
    int i = base + q;
    if (i < n) {
      off[i] = excl;
      cur[i] = excl;
    }
    excl += d[q];
  }
}

// ---------- CSR build: fill packed edge array ----------
__global__ __launch_bounds__(256)
void fill_kernel(const int* __restrict__ src, const int* __restrict__ dst,
                 const int* __restrict__ et, int* __restrict__ cur,
                 int* __restrict__ epk, int nEdges) {
  for (int e = blockIdx.x * 256 + threadIdx.x; e < nEdges; e += gridDim.x * 256) {
    int d = dst[e];
    int pos = atomicAdd(&cur[d], 1);
    epk[pos] = src[e] | (et[e] << 17);
  }
}

// ---------- gather-mean, 4-wide ILP edge walk ----------
__global__ __launch_bounds__(256)
void gather_mean_kernel(const int* __restrict__ off, const int* __restrict__ epk,
                        const float* __restrict__ H, const float* __restrict__ REL,
                        float* __restrict__ MEAN, int doBN, float* __restrict__ acc,
                        int nNodes) {
  const float4* H4 = (const float4*)H;
  const float4* R4 = (const float4*)REL;
  float4* M4 = (float4*)MEAN;
  int t = threadIdx.x;
  int j = t & 31;     // float4 lane within feature row
  int slot = t >> 5;  // 8 nodes per block
  float4 s1 = {0.f, 0.f, 0.f, 0.f}, s2 = {0.f, 0.f, 0.f, 0.f};
  for (int n = blockIdx.x * 8 + slot; n < nNodes; n += gridDim.x * 8) {
    int beg = off[n], end = off[n + 1];
    float4 a = {0.f, 0.f, 0.f, 0.f};
    int p = beg;
#pragma unroll 1
    for (; p + 4 <= end; p += 4) {
      // 4 independent packed-edge loads first (breaks the dependent chain),
      // then 8 independent row loads in flight together.
      int u0 = epk[p + 0];
      int u1 = epk[p + 1];
      int u2 = epk[p + 2];
      int u3 = epk[p + 3];
      float4 h0 = H4[(size_t)(u0 & 0x1FFFF) * 32 + j];
      float4 h1 = H4[(size_t)(u1 & 0x1FFFF) * 32 + j];
      float4 h2 = H4[(size_t)(u2 & 0x1FFFF) * 32 + j];
      float4 h3 = H4[(size_t)(u3 & 0x1FFFF) * 32 + j];
      float4 r0 = R4[(u0 >> 17) * 32 + j];
      float4 r1 = R4[(u1 >> 17) * 32 + j];
      float4 r2 = R4[(u2 >> 17) * 32 + j];
      float4 r3 = R4[(u3 >> 17) * 32 + j];
      a.x += (h0.x + r0.x) + (h1.x + r1.x) + (h2.x + r2.x) + (h3.x + r3.x);
      a.y += (h0.y + r0.y) + (h1.y + r1.y) + (h2.y + r2.y) + (h3.y + r3.y);
      a.z += (h0.z + r0.z) + (h1.z + r1.z) + (h2.z + r2.z) + (h3.z + r3.z);
      a.w += (h0.w + r0.w) + (h1.w + r1.w) + (h2.w + r2.w) + (h3.w + r3.w);
    }
#pragma unroll 1
    for (; p < end; ++p) {
      int u = epk[p];
      float4 hv = H4[(size_t)(u & 0x1FFFF) * 32 + j];
      float4 rv = R4[(u >> 17) * 32 + j];
      a.x += hv.x + rv.x; a.y += hv.y + rv.y;
      a.z += hv.z + rv.z; a.w += hv.w + rv.w;
    }
    float rd = (end > beg) ? 1.f / (float)(end - beg) : 0.f;
    a.x *= rd; a.y *= rd; a.z *= rd; a.w *= rd;
    M4[(size_t)n * 32 + j] = a;
    if (doBN) {
      s1.x += a.x; s1.y += a.y; s1.z += a.z; s1.w += a.w;
      s2.x += a.x * a.x; s2.y += a.y * a.y;
      s2.z += a.z * a.z; s2.w += a.w * a.w;
    }
  }
  if (doBN) {
    __shared__ float4 r1[8][32], r2[8][32];
    r1[slot][j] = s1;
    r2[slot][j] = s2;
    __syncthreads();
    if (slot == 0) {
      float4 a1 = r1[0][j], a2 = r2[0][j];
#pragma unroll
      for (int k = 1; k < 8; ++k) {
        float4 b1 = r1[k][j], b2 = r2[k][j];
        a1.x += b1.x; a1.y += b1.y; a1.z += b1.z; a1.w += b1.w;
        a2.x += b2.x; a2.y += b2.y; a2.z += b2.z; a2.w += b2.w;
      }
      atomicAdd(&acc[4 * j + 0], a1.x);
      atomicAdd(&acc[4 * j + 1], a1.y);
      atomicAdd(&acc[4 * j + 2], a1.z);
      atomicAdd(&acc[4 * j + 3], a1.w);
      atomicAdd(&acc[FEAT_D + 4 * j + 0], a2.x);
      atomicAdd(&acc[FEAT_D + 4 * j + 1], a2.y);
      atomicAdd(&acc[FEAT_D + 4 * j + 2], a2.z);
      atomicAdd(&acc[FEAT_D + 4 * j + 3], a2.w);
    }
  }
}

// ---------- H1[n] = relu(MEAN[n] @ aggre_W + b) ; one node per thread ----------
__global__ __launch_bounds__(256)
void h1_kernel(const float* __restrict__ mean, const float* __restrict__ W,
               const float* __restrict__ bias, float* __restrict__ H, int nNodes) {
  __shared__ float WT[FEAT_D * FEAT_D];  // WT[j*128+k] = W[k*128+j]
  __shared__ float bs[FEAT_D];
  int t = threadIdx.x;
  for (int i = t; i < FEAT_D * FEAT_D; i += 256) {
    int k = i >> 7, j = i & 127;
    WT[j * FEAT_D + k] = W[i];
  }
  if (t < FEAT_D) bs[t] = bias[t];
  __syncthreads();
  for (int n = blockIdx.x * 256 + t; n < nNodes; n += gridDim.x * 256) {
    float x[FEAT_D];
    const float4* xp = (const float4*)(mean + (size_t)n * FEAT_D);
#pragma unroll
    for (int q = 0; q < 32; ++q) {
      float4 v = xp[q];
      x[4 * q + 0] = v.x; x[4 * q + 1] = v.y;
      x[4 * q + 2] = v.z; x[4 * q + 3] = v.w;
    }
    float* orow = H + (size_t)n * FEAT_D;
    for (int j4 = 0; j4 < 32; ++j4) {
      float4 a;
      a.x = bs[4 * j4 + 0]; a.y = bs[4 * j4 + 1];
      a.z = bs[4 * j4 + 2]; a.w = bs[4 * j4 + 3];
      const float4* w0 = (const float4*)&WT[(4 * j4 + 0) * FEAT_D];
      const float4* w1 = (const float4*)&WT[(4 * j4 + 1) * FEAT_D];
      const float4* w2 = (const float4*)&WT[(4 * j4 + 2) * FEAT_D];
      const float4* w3 = (const float4*)&WT[(4 * j4 + 3) * FEAT_D];
#pragma unroll
      for (int q = 0; q < 32; ++q) {
        float4 v0 = w0[q], v1 = w1[q], v2 = w2[q], v3 = w3[q];
        a.x = fmaf(x[4*q+0], v0.x, a.x); a.x = fmaf(x[4*q+1], v0.y, a.x);
        a.x = fmaf(x[4*q+2], v0.z, a.x); a.x = fmaf(x[4*q+3], v0.w, a.x);
        a.y = fmaf(x[4*q+0], v1.x, a.y); a.y = fmaf(x[4*q+1], v1.y, a.y);
        a.y = fmaf(x[4*q+2], v1.z, a.y); a.y = fmaf(x[4*q+3], v1.w, a.y);
        a.z = fmaf(x[4*q+0], v2.x, a.z); a.z = fmaf(x[4*q+1], v2.y, a.z);
        a.z = fmaf(x[4*q+2], v2.z, a.z); a.z = fmaf(x[4*q+3], v2.w, a.z);
        a.w = fmaf(x[4*q+0], v3.x, a.w); a.w = fmaf(x[4*q+1], v3.y, a.w);
        a.w = fmaf(x[4*q+2], v3.z, a.w); a.w = fmaf(x[4*q+3], v3.w, a.w);
      }
      a.x = fmaxf(a.x, 0.f); a.y = fmaxf(a.y, 0.f);
      a.z = fmaxf(a.z, 0.f); a.w = fmaxf(a.w, 0.f);
      *(float4*)(orow + 4 * j4) = a;
    }
  }
}

// ---------- final: BN -> relu -> MLP 128->64->32->50 ; one node per thread ----------
__global__ __launch_bounds__(256)
void final_kernel(const float* __restrict__ mean, const float* __restrict__ acc,
                  const float* __restrict__ gamma, const float* __restrict__ beta,
                  const float* __restrict__ fc0w, const float* __restrict__ fc0b,
                  const float* __restrict__ fc1w, const float* __restrict__ fc1b,
                  const float* __restrict__ fc2w, const float* __restrict__ fc2b,
                  float* __restrict__ out, int nNodes) {
  __shared__ float W0T[64 * FEAT_D];   // W0T[j*128+k] = fc0w[k*64+j]
  __shared__ float W1L[64 * 32];       // fc1w as-is
  __shared__ float W2T[N_CLS * 32];    // W2T[c*32+jj] = fc2w[jj*50+c]
  __shared__ float sc[FEAT_D], sh[FEAT_D];
  __shared__ float b0[64], b1[32], b2[N_CLS];
  int t = threadIdx.x;
  for (int i = t; i < 64 * FEAT_D; i += 256) {
    int k = i >> 6, j = i & 63;
    W0T[j * FEAT_D + k] = fc0w[i];
  }
  for (int i = t; i < 64 * 32; i += 256) W1L[i] = fc1w[i];
  for (int i = t; i < 32 * N_CLS; i += 256) {
    int jj = i / N_CLS, c = i % N_CLS;
    W2T[c * 32 + jj] = fc2w[i];
  }
  if (t < FEAT_D) {
    float m = acc[t] * (1.f / (float)N_NODES);
    float v = acc[FEAT_D + t] * (1.f / (float)N_NODES) - m * m;
    float r = rsqrtf(v + BN_EPS);
    float g = gamma[t];
    sc[t] = r * g;
    sh[t] = beta[t] - m * r * g;
  }
  if (t < 64) b0[t] = fc0b[t];
  if (t < 32) b1[t] = fc1b[t];
  if (t < N_CLS) b2[t] = fc2b[t];
  __syncthreads();
  for (int n = blockIdx.x * 256 + t; n < nNodes; n += gridDim.x * 256) {
    float x[FEAT_D];
    const float4* xp = (const float4*)(mean + (size_t)n * FEAT_D);
#pragma unroll
    for (int q = 0; q < 32; ++q) {
      float4 v = xp[q];
      x[4*q+0] = fmaxf(fmaf(v.x, sc[4*q+0], sh[4*q+0]), 0.f);
      x[4*q+1] = fmaxf(fmaf(v.y, sc[4*q+1], sh[4*q+1]), 0.f);
      x[4*q+2] = fmaxf(fmaf(v.z, sc[4*q+2], sh[4*q+2]), 0.f);
      x[4*q+3] = fmaxf(fmaf(v.w, sc[4*q+3], sh[4*q+3]), 0.f);
    }
    float acc2[32];
#pragma unroll
    for (int jj = 0; jj < 32; ++jj) acc2[jj] = b1[jj];
    for (int j = 0; j < 64; ++j) {
      float a = b0[j];
      const float4* w = (const float4*)&W0T[j * FEAT_D];
#pragma unroll
      for (int q = 0; q < 32; ++q) {
        float4 v = w[q];
        a = fmaf(x[4*q+0], v.x, a); a = fmaf(x[4*q+1], v.y, a);
        a = fmaf(x[4*q+2], v.z, a); a = fmaf(x[4*q+3], v.w, a);
      }
      float h = fmaxf(a, 0.f);
      const float4* w1 = (const float4*)&W1L[j * 32];
#pragma unroll
      for (int q = 0; q < 8; ++q) {
        float4 v = w1[q];
        acc2[4*q+0] = fmaf(h, v.x, acc2[4*q+0]);
        acc2[4*q+1] = fmaf(h, v.y, acc2[4*q+1]);
        acc2[4*q+2] = fmaf(h, v.z, acc2[4*q+2]);
        acc2[4*q+3] = fmaf(h, v.w, acc2[4*q+3]);
      }
    }
    float h2[32];
#pragma unroll
    for (int jj = 0; jj < 32; ++jj) h2[jj] = fmaxf(acc2[jj], 0.f);
    float* orow = out + (size_t)n * N_CLS;
    for (int cc = 0; cc < N_CLS; ++cc) {
      float a = b2[cc];
      const float4* w = (const float4*)&W2T[cc * 32];
#pragma unroll
      for (int q = 0; q < 8; ++q) {
        float4 v = w[q];
        a = fmaf(h2[4*q+0], v.x, a); a = fmaf(h2[4*q+1], v.y, a);
        a = fmaf(h2[4*q+2], v.z, a); a = fmaf(h2[4*q+3], v.w, a);
      }
      orow[cc] = a;
    }
  }
}

extern "C" void kernel_launch(void* const* d_in, const int* in_sizes, int n_in,
                              void* d_out, int out_size, void* d_ws, size_t ws_size,
                              hipStream_t stream) {
  const int* edge_src = (const int*)d_in[0];
  const int* edge_dst = (const int*)d_in[1];
  const int* edge_type = (const int*)d_in[2];
  const float* emb_h = (const float*)d_in[3];
  const float* emb_e = (const float*)d_in[4];
  const float* rel_wt = (const float*)d_in[5];
  const float* W_h_init = (const float*)d_in[6];
  const float* W_e_init = (const float*)d_in[7];
  const float* aggre_W = (const float*)d_in[8];
  const float* aggre_b = (const float*)d_in[9];
  const float* bn_gamma = (const float*)d_in[10];
  const float* bn_beta = (const float*)d_in[11];
  const float* fc0_w = (const float*)d_in[12];
  const float* fc0_b = (const float*)d_in[13];
  const float* fc1_w = (const float*)d_in[14];
  const float* fc1_b = (const float*)d_in[15];
  const float* fc2_w = (const float*)d_in[16];
  const float* fc2_b = (const float*)d_in[17];
  float* out = (float*)d_out;

  // ---- workspace (ws): big float buffers only; total 102,554,624 B ----
  char* ws = (char*)d_ws;
  float* REL  = (float*)(ws);                    // 102,400
  float* WC   = (float*)(ws + 102400);           // 51,200
  float* H    = (float*)(ws + 153600);           // 51,200,000 (H0, then H1)
  float* MEAN = (float*)(ws + 51353600);         // 51,200,000
  float* ACC  = (float*)(ws + 102553600);        // 1,024

  // ---- CSR scratch lives in d_out (20 MB); final_kernel overwrites it last ----
  char* ob = (char*)d_out;
  int* EPK  = (int*)(ob);                        // 2,000,000  (500k packed edges)
  int* DEG  = (int*)(ob + 2000000);              // 400,000
  int* OFF  = (int*)(ob + 2400000);              // 400,004
  int* CUR  = (int*)(ob + 2800004);              // 400,004
  int* BSUM = (int*)(ob + 3200008);              // 392

  const int NODE_BLOCKS = (N_NODES + 255) / 256;  // 391
  const int GATHER_BLOCKS = 2048;

  hipMemsetAsync(ACC, 0, 1024, stream);

  rel_kernel<<<N_RELS, 128, 0, stream>>>(rel_wt, emb_e, W_e_init, REL);
  wcomb_kernel<<<INIT_D, 128, 0, stream>>>(W_h_init, aggre_W, WC);
  h0_kernel<<<NODE_BLOCKS, 256, 0, stream>>>(emb_h, WC, aggre_b, H, N_NODES);

  // ---- layer 0: build CSR and gather ----
  hipMemsetAsync(DEG, 0, 400000, stream);
  hist_kernel<<<1024, 256, 0, stream>>>(edge_dst, DEG, N_EDGES);
  scanA_kernel<<<NB_SCAN, 256, 0, stream>>>(DEG, BSUM, N_NODES);
  scanB_kernel<<<1, 1, 0, stream>>>(BSUM, NB_SCAN, OFF);
  scanC_kernel<<<NB_SCAN, 256, 0, stream>>>(DEG, BSUM, OFF, CUR, N_NODES);
  fill_kernel<<<1024, 256, 0, stream>>>(edge_src, edge_dst, edge_type, CUR, EPK,
                                        N_EDGES);
  gather_mean_kernel<<<GATHER_BLOCKS, 256, 0, stream>>>(OFF, EPK, H, REL, MEAN, 0,
                                                        ACC, N_NODES);

  h1_kernel<<<NODE_BLOCKS, 256, 0, stream>>>(MEAN, aggre_W, aggre_b, H, N_NODES);

  // ---- layer 1: rebuild CSR and gather (+BN stats) ----
  hipMemsetAsync(DEG, 0, 400000, stream);
  hist_kernel<<<1024, 256, 0, stream>>>(edge_dst + N_EDGES, DEG, N_EDGES);
  scanA_kernel<<<NB_SCAN, 256, 0, stream>>>(DEG, BSUM, N_NODES);
  scanB_kernel<<<1, 1, 0, stream>>>(BSUM, NB_SCAN, OFF);
  scanC_kernel<<<NB_SCAN, 256, 0, stream>>>(DEG, BSUM, OFF, CUR, N_NODES);
  fill_kernel<<<1024, 256, 0, stream>>>(edge_src + N_EDGES, edge_dst + N_EDGES,
                                        edge_type + N_EDGES, CUR, EPK, N_EDGES);
  gather_mean_kernel<<<GATHER_BLOCKS, 256, 0, stream>>>(OFF, EPK, H, REL, MEAN, 1,
                                                        ACC, N_NODES);

  final_kernel<<<NODE_BLOCKS, 256, 0, stream>>>(MEAN, ACC, bn_gamma, bn_beta,
                                                fc0_w, fc0_b, fc1_w, fc1_b,
                                                fc2_w, fc2_b, out, N_NODES);
}

// Round 5
// 760.582 us; speedup vs baseline: 1.0535x; 1.0535x over previous
//
#include <hip/hip_runtime.h>
#include <cstdint>
#include <cstddef>

#define N_NODES 100000
#define N_EDGES 500000
#define N_RELS  200
#define N_BASE  50
#define INIT_D  100
#define FEAT_D  128
#define N_CLS   50
#define BN_EPS  1e-5f

#define SCAN_BLK 1024
#define NB_SCAN  ((N_NODES + SCAN_BLK - 1) / SCAN_BLK)   // 98

typedef unsigned int uint;
typedef unsigned short ushort;

// bf16 helpers (RNE pack, cheap unpack)
__device__ inline uint packbf2(float a, float b) {
  uint ua = __float_as_uint(a); ua = (ua + 0x7fffu + ((ua >> 16) & 1u)) >> 16;
  uint ub = __float_as_uint(b); ub = (ub + 0x7fffu + ((ub >> 16) & 1u)) >> 16;
  return ua | (ub << 16);
}
__device__ inline float bf_lo(uint u) { return __uint_as_float(u << 16); }
__device__ inline float bf_hi(uint u) { return __uint_as_float(u & 0xffff0000u); }

// ---------- REL[r][f] = (rel_wt[r] @ emb_e) @ W_e_init ----------
__global__ __launch_bounds__(128)
void rel_kernel(const float* __restrict__ rel_wt, const float* __restrict__ emb_e,
                const float* __restrict__ W_e, float* __restrict__ REL) {
  int r = blockIdx.x;
  int t = threadIdx.x;
  __shared__ float T[INIT_D];
  if (t < INIT_D) {
    float a = 0.f;
    for (int b = 0; b < N_BASE; ++b)
      a += rel_wt[r * N_BASE + b] * emb_e[b * INIT_D + t];
    T[t] = a;
  }
  __syncthreads();
  float a = 0.f;
  for (int k = 0; k < INIT_D; ++k)
    a += T[k] * W_e[k * FEAT_D + t];
  REL[r * FEAT_D + t] = a;
}

// ---------- Wcomb = W_h_init @ aggre_W  (100 x 128) ----------
__global__ __launch_bounds__(128)
void wcomb_kernel(const float* __restrict__ W_h, const float* __restrict__ aggre_W,
                  float* __restrict__ WC) {
  int i = blockIdx.x;
  int j = threadIdx.x;
  __shared__ float row[FEAT_D];
  row[j] = W_h[i * FEAT_D + j];
  __syncthreads();
  float a = 0.f;
  for (int f = 0; f < FEAT_D; ++f)
    a += row[f] * aggre_W[f * FEAT_D + j];
  WC[i * FEAT_D + j] = a;
}

// ---------- H0[n] = relu(emb_h[n] @ WC + b) -> bf16 rows ----------
__global__ __launch_bounds__(256)
void h0_kernel(const float* __restrict__ emb_h, const float* __restrict__ WC,
               const float* __restrict__ bias, ushort* __restrict__ H, int nNodes) {
  __shared__ float WT[FEAT_D * INIT_D];  // WT[j*100+k] = WC[k*128+j]
  __shared__ float bs[FEAT_D];
  int t = threadIdx.x;
  for (int i = t; i < FEAT_D * INIT_D; i += 256) {
    int k = i >> 7, j = i & 127;
    WT[j * INIT_D + k] = WC[i];
  }
  if (t < FEAT_D) bs[t] = bias[t];
  __syncthreads();
  for (int n = blockIdx.x * 256 + t; n < nNodes; n += gridDim.x * 256) {
    float x[INIT_D];
    const float4* xp = (const float4*)(emb_h + (size_t)n * INIT_D);
#pragma unroll
    for (int q = 0; q < 25; ++q) {
      float4 v = xp[q];
      x[4 * q + 0] = v.x; x[4 * q + 1] = v.y; x[4 * q + 2] = v.z; x[4 * q + 3] = v.w;
    }
    uint2* orow = (uint2*)(H + (size_t)n * FEAT_D);  // 32 uint2 per row
    for (int j4 = 0; j4 < 32; ++j4) {
      float4 a;
      a.x = bs[4 * j4 + 0]; a.y = bs[4 * j4 + 1];
      a.z = bs[4 * j4 + 2]; a.w = bs[4 * j4 + 3];
      const float4* w0 = (const float4*)&WT[(4 * j4 + 0) * INIT_D];
      const float4* w1 = (const float4*)&WT[(4 * j4 + 1) * INIT_D];
      const float4* w2 = (const float4*)&WT[(4 * j4 + 2) * INIT_D];
      const float4* w3 = (const float4*)&WT[(4 * j4 + 3) * INIT_D];
#pragma unroll
      for (int q = 0; q < 25; ++q) {
        float4 v0 = w0[q], v1 = w1[q], v2 = w2[q], v3 = w3[q];
        a.x = fmaf(x[4*q+0], v0.x, a.x); a.x = fmaf(x[4*q+1], v0.y, a.x);
        a.x = fmaf(x[4*q+2], v0.z, a.x); a.x = fmaf(x[4*q+3], v0.w, a.x);
        a.y = fmaf(x[4*q+0], v1.x, a.y); a.y = fmaf(x[4*q+1], v1.y, a.y);
        a.y = fmaf(x[4*q+2], v1.z, a.y); a.y = fmaf(x[4*q+3], v1.w, a.y);
        a.z = fmaf(x[4*q+0], v2.x, a.z); a.z = fmaf(x[4*q+1], v2.y, a.z);
        a.z = fmaf(x[4*q+2], v2.z, a.z); a.z = fmaf(x[4*q+3], v2.w, a.z);
        a.w = fmaf(x[4*q+0], v3.x, a.w); a.w = fmaf(x[4*q+1], v3.y, a.w);
        a.w = fmaf(x[4*q+2], v3.z, a.w); a.w = fmaf(x[4*q+3], v3.w, a.w);
      }
      a.x = fmaxf(a.x, 0.f); a.y = fmaxf(a.y, 0.f);
      a.z = fmaxf(a.z, 0.f); a.w = fmaxf(a.w, 0.f);
      uint2 pk; pk.x = packbf2(a.x, a.y); pk.y = packbf2(a.z, a.w);
      orow[j4] = pk;
    }
  }
}

// ---------- CSR build: histogram of dst ----------
__global__ __launch_bounds__(256)
void hist_kernel(const int* __restrict__ dst, int* __restrict__ deg, int nEdges) {
  for (int e = blockIdx.x * 256 + threadIdx.x; e < nEdges; e += gridDim.x * 256)
    atomicAdd(&deg[dst[e]], 1);
}

// ---------- CSR build: per-block sums of deg ----------
__global__ __launch_bounds__(256)
void scanA_kernel(const int* __restrict__ deg, int* __restrict__ bsum, int n) {
  __shared__ int red[256];
  int t = threadIdx.x;
  int base = blockIdx.x * SCAN_BLK + t * 4;
  int s = 0;
#pragma unroll
  for (int q = 0; q < 4; ++q) {
    int i = base + q;
    s += (i < n) ? deg[i] : 0;
  }
  red[t] = s;
  __syncthreads();
  for (int off = 128; off > 0; off >>= 1) {
    if (t < off) red[t] += red[t + off];
    __syncthreads();
  }
  if (t == 0) bsum[blockIdx.x] = red[0];
}

// ---------- CSR build: sequential scan of block sums (tiny) ----------
__global__ void scanB_kernel(int* __restrict__ bsum, int nb, int* __restrict__ off) {
  int run = 0;
  for (int i = 0; i < nb; ++i) {
    int v = bsum[i];
    bsum[i] = run;
    run += v;
  }
  off[N_NODES] = run;
}

// ---------- CSR build: final offsets (exclusive scan) + cursor copy ----------
__global__ __launch_bounds__(256)
void scanC_kernel(const int* __restrict__ deg, const int* __restrict__ bsum,
                  int* __restrict__ off, int* __restrict__ cur, int n) {
  __shared__ int lds[256];
  int t = threadIdx.x;
  int base = blockIdx.x * SCAN_BLK + t * 4;
  int d[4];
  int s = 0;
#pragma unroll
  for (int q = 0; q < 4; ++q) {
    int i = base + q;
    d[q] = (i < n) ? deg[i] : 0;
    s += d[q];
  }
  lds[t] = s;
  __syncthreads();
  for (int o = 1; o < 256; o <<= 1) {
    int v = (t >= o) ? lds[t - o] : 0;
    __syncthreads();
    lds[t] += v;
    __syncthreads();
  }
  int excl = lds[t] - s + bsum[blockIdx.x];
#pragma unroll
  for (int q = 0; q < 4; ++q) {
    int i = base + q;
    if (i < n) {
      off[i] = excl;
      cur[i] = excl;
    }
    excl += d[q];
  }
}

// ---------- CSR build: fill packed edge array ----------
__global__ __launch_bounds__(256)
void fill_kernel(const int* __restrict__ src, const int* __restrict__ dst,
                 const int* __restrict__ et, int* __restrict__ cur,
                 int* __restrict__ epk, int nEdges) {
  for (int e = blockIdx.x * 256 + threadIdx.x; e < nEdges; e += gridDim.x * 256) {
    int d = dst[e];
    int pos = atomicAdd(&cur[d], 1);
    epk[pos] = src[e] | (et[e] << 17);
  }
}

// ---------- gather-mean over bf16 H rows, fp32 REL + accum ----------
__global__ __launch_bounds__(256)
void gather_mean_kernel(const int* __restrict__ off, const int* __restrict__ epk,
                        const ushort* __restrict__ H, const float* __restrict__ REL,
                        float* __restrict__ MEAN, int doBN, float* __restrict__ acc,
                        int nNodes) {
  const uint2* H2 = (const uint2*)H;     // 32 uint2 per 128-feat row (4 bf16 each)
  const float4* R4 = (const float4*)REL;
  float4* M4 = (float4*)MEAN;
  int t = threadIdx.x;
  int j = t & 31;     // 4-feature group within row
  int slot = t >> 5;  // 8 nodes per block
  float4 s1 = {0.f, 0.f, 0.f, 0.f}, s2 = {0.f, 0.f, 0.f, 0.f};
  for (int n = blockIdx.x * 8 + slot; n < nNodes; n += gridDim.x * 8) {
    int beg = off[n], end = off[n + 1];
    float4 a = {0.f, 0.f, 0.f, 0.f};
    int p = beg;
#pragma unroll 1
    for (; p + 4 <= end; p += 4) {
      int u0 = epk[p + 0];
      int u1 = epk[p + 1];
      int u2 = epk[p + 2];
      int u3 = epk[p + 3];
      uint2 h0 = H2[(size_t)(u0 & 0x1FFFF) * 32 + j];
      uint2 h1 = H2[(size_t)(u1 & 0x1FFFF) * 32 + j];
      uint2 h2 = H2[(size_t)(u2 & 0x1FFFF) * 32 + j];
      uint2 h3 = H2[(size_t)(u3 & 0x1FFFF) * 32 + j];
      float4 r0 = R4[(u0 >> 17) * 32 + j];
      float4 r1 = R4[(u1 >> 17) * 32 + j];
      float4 r2 = R4[(u2 >> 17) * 32 + j];
      float4 r3 = R4[(u3 >> 17) * 32 + j];
      a.x += (bf_lo(h0.x) + r0.x) + (bf_lo(h1.x) + r1.x) +
             (bf_lo(h2.x) + r2.x) + (bf_lo(h3.x) + r3.x);
      a.y += (bf_hi(h0.x) + r0.y) + (bf_hi(h1.x) + r1.y) +
             (bf_hi(h2.x) + r2.y) + (bf_hi(h3.x) + r3.y);
      a.z += (bf_lo(h0.y) + r0.z) + (bf_lo(h1.y) + r1.z) +
             (bf_lo(h2.y) + r2.z) + (bf_lo(h3.y) + r3.z);
      a.w += (bf_hi(h0.y) + r0.w) + (bf_hi(h1.y) + r1.w) +
             (bf_hi(h2.y) + r2.w) + (bf_hi(h3.y) + r3.w);
    }
#pragma unroll 1
    for (; p < end; ++p) {
      int u = epk[p];
      uint2 hv = H2[(size_t)(u & 0x1FFFF) * 32 + j];
      float4 rv = R4[(u >> 17) * 32 + j];
      a.x += bf_lo(hv.x) + rv.x; a.y += bf_hi(hv.x) + rv.y;
      a.z += bf_lo(hv.y) + rv.z; a.w += bf_hi(hv.y) + rv.w;
    }
    float rd = (end > beg) ? 1.f / (float)(end - beg) : 0.f;
    a.x *= rd; a.y *= rd; a.z *= rd; a.w *= rd;
    M4[(size_t)n * 32 + j] = a;
    if (doBN) {
      s1.x += a.x; s1.y += a.y; s1.z += a.z; s1.w += a.w;
      s2.x += a.x * a.x; s2.y += a.y * a.y;
      s2.z += a.z * a.z; s2.w += a.w * a.w;
    }
  }
  if (doBN) {
    __shared__ float4 r1[8][32], r2[8][32];
    r1[slot][j] = s1;
    r2[slot][j] = s2;
    __syncthreads();
    if (slot == 0) {
      float4 a1 = r1[0][j], a2 = r2[0][j];
#pragma unroll
      for (int k = 1; k < 8; ++k) {
        float4 b1 = r1[k][j], b2 = r2[k][j];
        a1.x += b1.x; a1.y += b1.y; a1.z += b1.z; a1.w += b1.w;
        a2.x += b2.x; a2.y += b2.y; a2.z += b2.z; a2.w += b2.w;
      }
      atomicAdd(&acc[4 * j + 0], a1.x);
      atomicAdd(&acc[4 * j + 1], a1.y);
      atomicAdd(&acc[4 * j + 2], a1.z);
      atomicAdd(&acc[4 * j + 3], a1.w);
      atomicAdd(&acc[FEAT_D + 4 * j + 0], a2.x);
      atomicAdd(&acc[FEAT_D + 4 * j + 1], a2.y);
      atomicAdd(&acc[FEAT_D + 4 * j + 2], a2.z);
      atomicAdd(&acc[FEAT_D + 4 * j + 3], a2.w);
    }
  }
}

// ---------- H1[n] = relu(MEAN[n] @ aggre_W + b) -> bf16 rows ----------
__global__ __launch_bounds__(256)
void h1_kernel(const float* __restrict__ mean, const float* __restrict__ W,
               const float* __restrict__ bias, ushort* __restrict__ H, int nNodes) {
  __shared__ float WT[FEAT_D * FEAT_D];  // WT[j*128+k] = W[k*128+j]
  __shared__ float bs[FEAT_D];
  int t = threadIdx.x;
  for (int i = t; i < FEAT_D * FEAT_D; i += 256) {
    int k = i >> 7, j = i & 127;
    WT[j * FEAT_D + k] = W[i];
  }
  if (t < FEAT_D) bs[t] = bias[t];
  __syncthreads();
  for (int n = blockIdx.x * 256 + t; n < nNodes; n += gridDim.x * 256) {
    float x[FEAT_D];
    const float4* xp = (const float4*)(mean + (size_t)n * FEAT_D);
#pragma unroll
    for (int q = 0; q < 32; ++q) {
      float4 v = xp[q];
      x[4 * q + 0] = v.x; x[4 * q + 1] = v.y;
      x[4 * q + 2] = v.z; x[4 * q + 3] = v.w;
    }
    uint2* orow = (uint2*)(H + (size_t)n * FEAT_D);
    for (int j4 = 0; j4 < 32; ++j4) {
      float4 a;
      a.x = bs[4 * j4 + 0]; a.y = bs[4 * j4 + 1];
      a.z = bs[4 * j4 + 2]; a.w = bs[4 * j4 + 3];
      const float4* w0 = (const float4*)&WT[(4 * j4 + 0) * FEAT_D];
      const float4* w1 = (const float4*)&WT[(4 * j4 + 1) * FEAT_D];
      const float4* w2 = (const float4*)&WT[(4 * j4 + 2) * FEAT_D];
      const float4* w3 = (const float4*)&WT[(4 * j4 + 3) * FEAT_D];
#pragma unroll
      for (int q = 0; q < 32; ++q) {
        float4 v0 = w0[q], v1 = w1[q], v2 = w2[q], v3 = w3[q];
        a.x = fmaf(x[4*q+0], v0.x, a.x); a.x = fmaf(x[4*q+1], v0.y, a.x);
        a.x = fmaf(x[4*q+2], v0.z, a.x); a.x = fmaf(x[4*q+3], v0.w, a.x);
        a.y = fmaf(x[4*q+0], v1.x, a.y); a.y = fmaf(x[4*q+1], v1.y, a.y);
        a.y = fmaf(x[4*q+2], v1.z, a.y); a.y = fmaf(x[4*q+3], v1.w, a.y);
        a.z = fmaf(x[4*q+0], v2.x, a.z); a.z = fmaf(x[4*q+1], v2.y, a.z);
        a.z = fmaf(x[4*q+2], v2.z, a.z); a.z = fmaf(x[4*q+3], v2.w, a.z);
        a.w = fmaf(x[4*q+0], v3.x, a.w); a.w = fmaf(x[4*q+1], v3.y, a.w);
        a.w = fmaf(x[4*q+2], v3.z, a.w); a.w = fmaf(x[4*q+3], v3.w, a.w);
      }
      a.x = fmaxf(a.x, 0.f); a.y = fmaxf(a.y, 0.f);
      a.z = fmaxf(a.z, 0.f); a.w = fmaxf(a.w, 0.f);
      uint2 pk; pk.x = packbf2(a.x, a.y); pk.y = packbf2(a.z, a.w);
      orow[j4] = pk;
    }
  }
}

// ---------- final: BN -> relu -> MLP 128->64->32->50 ; one node per thread ----------
__global__ __launch_bounds__(256)
void final_kernel(const float* __restrict__ mean, const float* __restrict__ acc,
                  const float* __restrict__ gamma, const float* __restrict__ beta,
                  const float* __restrict__ fc0w, const float* __restrict__ fc0b,
                  const float* __restrict__ fc1w, const float* __restrict__ fc1b,
                  const float* __restrict__ fc2w, const float* __restrict__ fc2b,
                  float* __restrict__ out, int nNodes) {
  __shared__ float W0T[64 * FEAT_D];
  __shared__ float W1L[64 * 32];
  __shared__ float W2T[N_CLS * 32];
  __shared__ float sc[FEAT_D], sh[FEAT_D];
  __shared__ float b0[64], b1[32], b2[N_CLS];
  int t = threadIdx.x;
  for (int i = t; i < 64 * FEAT_D; i += 256) {
    int k = i >> 6, j = i & 63;
    W0T[j * FEAT_D + k] = fc0w[i];
  }
  for (int i = t; i < 64 * 32; i += 256) W1L[i] = fc1w[i];
  for (int i = t; i < 32 * N_CLS; i += 256) {
    int jj = i / N_CLS, c = i % N_CLS;
    W2T[c * 32 + jj] = fc2w[i];
  }
  if (t < FEAT_D) {
    float m = acc[t] * (1.f / (float)N_NODES);
    float v = acc[FEAT_D + t] * (1.f / (float)N_NODES) - m * m;
    float r = rsqrtf(v + BN_EPS);
    float g = gamma[t];
    sc[t] = r * g;
    sh[t] = beta[t] - m * r * g;
  }
  if (t < 64) b0[t] = fc0b[t];
  if (t < 32) b1[t] = fc1b[t];
  if (t < N_CLS) b2[t] = fc2b[t];
  __syncthreads();
  for (int n = blockIdx.x * 256 + t; n < nNodes; n += gridDim.x * 256) {
    float x[FEAT_D];
    const float4* xp = (const float4*)(mean + (size_t)n * FEAT_D);
#pragma unroll
    for (int q = 0; q < 32; ++q) {
      float4 v = xp[q];
      x[4*q+0] = fmaxf(fmaf(v.x, sc[4*q+0], sh[4*q+0]), 0.f);
      x[4*q+1] = fmaxf(fmaf(v.y, sc[4*q+1], sh[4*q+1]), 0.f);
      x[4*q+2] = fmaxf(fmaf(v.z, sc[4*q+2], sh[4*q+2]), 0.f);
      x[4*q+3] = fmaxf(fmaf(v.w, sc[4*q+3], sh[4*q+3]), 0.f);
    }
    float acc2[32];
#pragma unroll
    for (int jj = 0; jj < 32; ++jj) acc2[jj] = b1[jj];
    for (int j = 0; j < 64; ++j) {
      float a = b0[j];
      const float4* w = (const float4*)&W0T[j * FEAT_D];
#pragma unroll
      for (int q = 0; q < 32; ++q) {
        float4 v = w[q];
        a = fmaf(x[4*q+0], v.x, a); a = fmaf(x[4*q+1], v.y, a);
        a = fmaf(x[4*q+2], v.z, a); a = fmaf(x[4*q+3], v.w, a);
      }
      float h = fmaxf(a, 0.f);
      const float4* w1 = (const float4*)&W1L[j * 32];
#pragma unroll
      for (int q = 0; q < 8; ++q) {
        float4 v = w1[q];
        acc2[4*q+0] = fmaf(h, v.x, acc2[4*q+0]);
        acc2[4*q+1] = fmaf(h, v.y, acc2[4*q+1]);
        acc2[4*q+2] = fmaf(h, v.z, acc2[4*q+2]);
        acc2[4*q+3] = fmaf(h, v.w, acc2[4*q+3]);
      }
    }
    float h2[32];
#pragma unroll
    for (int jj = 0; jj < 32; ++jj) h2[jj] = fmaxf(acc2[jj], 0.f);
    float* orow = out + (size_t)n * N_CLS;
    for (int cc = 0; cc < N_CLS; ++cc) {
      float a = b2[cc];
      const float4* w = (const float4*)&W2T[cc * 32];
#pragma unroll
      for (int q = 0; q < 8; ++q) {
        float4 v = w[q];
        a = fmaf(h2[4*q+0], v.x, a); a = fmaf(h2[4*q+1], v.y, a);
        a = fmaf(h2[4*q+2], v.z, a); a = fmaf(h2[4*q+3], v.w, a);
      }
      orow[cc] = a;
    }
  }
}

extern "C" void kernel_launch(void* const* d_in, const int* in_sizes, int n_in,
                              void* d_out, int out_size, void* d_ws, size_t ws_size,
                              hipStream_t stream) {
  const int* edge_src = (const int*)d_in[0];
  const int* edge_dst = (const int*)d_in[1];
  const int* edge_type = (const int*)d_in[2];
  const float* emb_h = (const float*)d_in[3];
  const float* emb_e = (const float*)d_in[4];
  const float* rel_wt = (const float*)d_in[5];
  const float* W_h_init = (const float*)d_in[6];
  const float* W_e_init = (const float*)d_in[7];
  const float* aggre_W = (const float*)d_in[8];
  const float* aggre_b = (const float*)d_in[9];
  const float* bn_gamma = (const float*)d_in[10];
  const float* bn_beta = (const float*)d_in[11];
  const float* fc0_w = (const float*)d_in[12];
  const float* fc0_b = (const float*)d_in[13];
  const float* fc1_w = (const float*)d_in[14];
  const float* fc1_b = (const float*)d_in[15];
  const float* fc2_w = (const float*)d_in[16];
  const float* fc2_b = (const float*)d_in[17];
  float* out = (float*)d_out;

  // ---- workspace layout (bytes): ~77 MB ----
  char* ws = (char*)d_ws;
  float*  REL  = (float*)(ws);                    // 102,400
  float*  WC   = (float*)(ws + 102400);           // 51,200
  ushort* H    = (ushort*)(ws + 153600);          // 100000*128*2 = 25,600,000
  float*  MEAN = (float*)(ws + 25753600);         // 51,200,000
  float*  ACC  = (float*)(ws + 76953600);         // 1,024

  // ---- CSR scratch lives in d_out (20 MB); final_kernel overwrites it last ----
  char* ob = (char*)d_out;
  int* EPK  = (int*)(ob);                        // 2,000,000
  int* DEG  = (int*)(ob + 2000000);              // 400,000
  int* OFF  = (int*)(ob + 2400000);              // 400,004
  int* CUR  = (int*)(ob + 2800004);              // 400,004
  int* BSUM = (int*)(ob + 3200008);              // 392

  const int NODE_BLOCKS = (N_NODES + 255) / 256;  // 391
  const int GATHER_BLOCKS = 2048;

  hipMemsetAsync(ACC, 0, 1024, stream);

  rel_kernel<<<N_RELS, 128, 0, stream>>>(rel_wt, emb_e, W_e_init, REL);
  wcomb_kernel<<<INIT_D, 128, 0, stream>>>(W_h_init, aggre_W, WC);
  h0_kernel<<<NODE_BLOCKS, 256, 0, stream>>>(emb_h, WC, aggre_b, H, N_NODES);

  // ---- layer 0: build CSR and gather ----
  hipMemsetAsync(DEG, 0, 400000, stream);
  hist_kernel<<<1024, 256, 0, stream>>>(edge_dst, DEG, N_EDGES);
  scanA_kernel<<<NB_SCAN, 256, 0, stream>>>(DEG, BSUM, N_NODES);
  scanB_kernel<<<1, 1, 0, stream>>>(BSUM, NB_SCAN, OFF);
  scanC_kernel<<<NB_SCAN, 256, 0, stream>>>(DEG, BSUM, OFF, CUR, N_NODES);
  fill_kernel<<<1024, 256, 0, stream>>>(edge_src, edge_dst, edge_type, CUR, EPK,
                                        N_EDGES);
  gather_mean_kernel<<<GATHER_BLOCKS, 256, 0, stream>>>(OFF, EPK, H, REL, MEAN, 0,
                                                        ACC, N_NODES);

  h1_kernel<<<NODE_BLOCKS, 256, 0, stream>>>(MEAN, aggre_W, aggre_b, H, N_NODES);

  // ---- layer 1: rebuild CSR and gather (+BN stats) ----
  hipMemsetAsync(DEG, 0, 400000, stream);
  hist_kernel<<<1024, 256, 0, stream>>>(edge_dst + N_EDGES, DEG, N_EDGES);
  scanA_kernel<<<NB_SCAN, 256, 0, stream>>>(DEG, BSUM, N_NODES);
  scanB_kernel<<<1, 1, 0, stream>>>(BSUM, NB_SCAN, OFF);
  scanC_kernel<<<NB_SCAN, 256, 0, stream>>>(DEG, BSUM, OFF, CUR, N_NODES);
  fill_kernel<<<1024, 256, 0, stream>>>(edge_src + N_EDGES, edge_dst + N_EDGES,
                                        edge_type + N_EDGES, CUR, EPK, N_EDGES);
  gather_mean_kernel<<<GATHER_BLOCKS, 256, 0, stream>>>(OFF, EPK, H, REL, MEAN, 1,
                                                        ACC, N_NODES);

  final_kernel<<<NODE_BLOCKS, 256, 0, stream>>>(MEAN, ACC, bn_gamma, bn_beta,
                                                fc0_w, fc0_b, fc1_w, fc1_b,
                                                fc2_w, fc2_b, out, N_NODES);
}